// Round 5
// baseline (683.012 us; speedup 1.0000x reference)
//
#include <hip/hip_runtime.h>
#include <hip/hip_bf16.h>

#define NUM_ENT   50000
#define NUM_RELC  500
#define KTOP      50
#define EMB       400
#define FEAT      1000
#define N_NODES   50500
#define N_EDGES   400000
#define BATCH     4096
#define RELM1     499     // NUM_REL - 1

// padded GEMM dims
#define KP   1024         // FEAT padded to mult of 64
#define MP   50560        // N_NODES padded to 395*128
#define NP   512          // EMB padded to mult of 128

#define NB_SCAN ((N_NODES + 255) / 256)   // 198

typedef __attribute__((ext_vector_type(8))) short short8;
typedef __attribute__((ext_vector_type(4))) float f32x4;

__device__ __forceinline__ ushort f2bf(float x) {
    __hip_bfloat16 h = __float2bfloat16(x);
    return *reinterpret_cast<ushort*>(&h);
}

// ---------------- logits: rel_feat @ Wp.T + bp  (499 dots of length 1000) ----
__global__ void logits_kernel(const float* __restrict__ nf, const float* __restrict__ Wp,
                              const float* __restrict__ bp, float* __restrict__ logits) {
    __shared__ float red[256];
    int i = blockIdx.x, t = threadIdx.x;
    float s = 0.f;
    for (int k = t; k < FEAT; k += 256) s += nf[(size_t)i * FEAT + k] * Wp[k];
    red[t] = s; __syncthreads();
    for (int st = 128; st > 0; st >>= 1) { if (t < st) red[t] += red[t + st]; __syncthreads(); }
    if (t == 0) logits[i] = red[0] + bp[0];
}

// ---------------- softmax over 499 + top-50 (sorted ascending) ---------------
__global__ void topk_kernel(const float* __restrict__ logits, int* __restrict__ idxbuf,
                            float* __restrict__ probsel) {
    __shared__ float l[RELM1];
    __shared__ float p[RELM1];
    __shared__ int   flag[RELM1];
    __shared__ float red[512];
    int t = threadIdx.x;  // 512 threads
    float v = (t < RELM1) ? logits[t] : -1e30f;
    if (t < RELM1) l[t] = v;
    red[t] = v; __syncthreads();
    for (int s = 256; s > 0; s >>= 1) { if (t < s) red[t] = fmaxf(red[t], red[t + s]); __syncthreads(); }
    float m = red[0]; __syncthreads();
    float e = (t < RELM1) ? expf(v - m) : 0.f;
    red[t] = e; __syncthreads();
    for (int s = 256; s > 0; s >>= 1) { if (t < s) red[t] += red[t + s]; __syncthreads(); }
    float denom = red[0];
    if (t < RELM1) p[t] = e / denom;
    __syncthreads();
    if (t < RELM1) {
        float lv = l[t]; int cnt = 0;
        for (int j = 0; j < RELM1; j++) {
            float lj = l[j];
            cnt += (lj > lv) || (lj == lv && j < t);
        }
        flag[t] = (cnt < KTOP);
    }
    __syncthreads();
    if (t == 0) {
        int n = 0;
        for (int i = 0; i < RELM1; i++)
            if (flag[i]) { idxbuf[n] = i; probsel[n] = p[i]; n++; }
    }
}

// ---------------- ra = concat(anchor, num_feature[idx]*prob[idx]) ------------
__global__ void build_ra(const float* __restrict__ anchor, const float* __restrict__ nf,
                         const int* __restrict__ idxbuf, const float* __restrict__ probsel,
                         float* __restrict__ ra) {
    int r = blockIdx.x, t = threadIdx.x;
    if (r < KTOP) {
        for (int k = t; k < FEAT; k += 256) ra[r * FEAT + k] = anchor[r * FEAT + k];
    } else {
        int j = r - KTOP; int src = idxbuf[j]; float pp = probsel[j];
        for (int k = t; k < FEAT; k += 256) ra[r * FEAT + k] = nf[(size_t)src * FEAT + k] * pp;
    }
}

// ---------------- degree + dinv (small graph, float path) --------------------
__global__ void deg_kernel(const int* __restrict__ ei, int nedges, float* __restrict__ deg) {
    int e = blockIdx.x * 256 + threadIdx.x;
    if (e < nedges) { int dst = ei[nedges + e]; atomicAdd(&deg[dst], 1.0f); }
}
__global__ void dinv_kernel(float* __restrict__ deg, int n) {
    int i = blockIdx.x * 256 + threadIdx.x;
    if (i < n) deg[i] = 1.0f / sqrtf(deg[i] + 1.0f);
}

// ---------------- small GCN scatter + finalize -------------------------------
__global__ void scatter_small(const int* __restrict__ ei, const float* __restrict__ raw,
                              const float* __restrict__ dinv_s, float* __restrict__ acc) {
    int wave = threadIdx.x >> 6, lane = threadIdx.x & 63;
    int e = blockIdx.x * 4 + wave;
    if (e >= 2000) return;
    int src = ei[e], dst = ei[2000 + e];
    float c = dinv_s[src] * dinv_s[dst];
    const float* rs = raw + (size_t)src * FEAT;
    float* ad = acc + (size_t)dst * FEAT;
    for (int k = lane; k < FEAT; k += 64) atomicAdd(&ad[k], rs[k] * c);
}
__global__ void finalize_small(const float* __restrict__ raw, const float* __restrict__ dinv_s,
                               const float* __restrict__ ba, float* __restrict__ x1s) {
    int r = blockIdx.x, t = threadIdx.x;
    float d2 = dinv_s[r] * dinv_s[r];
    for (int k = t; k < FEAT; k += 256) {
        float v = x1s[r * FEAT + k] + raw[r * FEAT + k] * d2 + ba[k];
        x1s[r * FEAT + k] = fmaxf(v, 0.f);
    }
}

// ---------------- big graph: CSR build ---------------------------------------
__global__ void hist_kernel(const int* __restrict__ ei, int* __restrict__ cnt) {
    int e = blockIdx.x * 256 + threadIdx.x;
    if (e < N_EDGES) atomicAdd(&cnt[ei[N_EDGES + e]], 1);
}
__global__ void dinv_from_cnt(const int* __restrict__ cnt, float* __restrict__ dinv) {
    int i = blockIdx.x * 256 + threadIdx.x;
    if (i < N_NODES) dinv[i] = rsqrtf((float)cnt[i] + 1.0f);
}
__global__ void scan_blocks(const int* __restrict__ cnt, int* __restrict__ offs,
                            int* __restrict__ partials) {
    __shared__ int s[256];
    int b = blockIdx.x, t = threadIdx.x;
    int i = b * 256 + t;
    int v = (i < N_NODES) ? cnt[i] : 0;
    s[t] = v; __syncthreads();
    for (int off = 1; off < 256; off <<= 1) {
        int add = (t >= off) ? s[t - off] : 0;
        __syncthreads();
        s[t] += add;
        __syncthreads();
    }
    if (i < N_NODES) offs[i] = s[t] - v;   // exclusive scan within block
    if (t == 255) partials[b] = s[t];
}
__global__ void scan_carry(int* __restrict__ partials) {
    __shared__ int s[256];
    int t = threadIdx.x;
    int v = (t < NB_SCAN) ? partials[t] : 0;
    s[t] = v; __syncthreads();
    for (int off = 1; off < 256; off <<= 1) {
        int add = (t >= off) ? s[t - off] : 0;
        __syncthreads();
        s[t] += add;
        __syncthreads();
    }
    if (t < NB_SCAN) partials[t] = s[t] - v;   // exclusive
}
__global__ void scan_add(int* __restrict__ offs, const int* __restrict__ partials) {
    int b = blockIdx.x; int i = b * 256 + threadIdx.x;
    if (i < N_NODES) offs[i] += partials[b];
}
__global__ void fill_csr(const int* __restrict__ ei, const int* __restrict__ offs,
                         int* __restrict__ cursor, const float* __restrict__ dinv,
                         int* __restrict__ esrc, float* __restrict__ ecoef) {
    int e = blockIdx.x * 256 + threadIdx.x;
    if (e >= N_EDGES) return;
    int src = ei[e], dst = ei[N_EDGES + e];
    int pos = offs[dst] + atomicAdd(&cursor[dst], 1);
    esrc[pos] = src;
    ecoef[pos] = dinv[src] * dinv[dst];
}

// ---------------- LDS-tiled transpose-convert: dst[n][KP] = bf16(src[k][n]) --
__global__ void transpose_bf16(const float* __restrict__ src, int K, int N,
                               ushort* __restrict__ dst) {
    __shared__ float tile[64][65];
    int k0 = blockIdx.x * 64, n0 = blockIdx.y * 64;
    int tx = threadIdx.x & 63, ty = threadIdx.x >> 6;   // 64 x 4
    for (int i = ty; i < 64; i += 4) {
        int k = k0 + i, n = n0 + tx;
        tile[i][tx] = (k < K && n < N) ? src[(size_t)k * N + n] : 0.f;
    }
    __syncthreads();
    for (int i = ty; i < 64; i += 4) {
        int n = n0 + i, k = k0 + tx;
        dst[(size_t)n * KP + k] = f2bf(tile[tx][i]);
    }
}

// ---------------- MFMA GEMM: C[M][ldc] = bf16(A_f32[*,FEAT]) @ Bt(bf16,[*,KP])^T
// 128x128 tile, BK=64, 4 waves (2x2). A: f32 reg-staged + in-kernel bf16 convert
// into XOR-swizzled LDS. B: global_load_lds with pre-swizzled source (rule #21).
template <typename OutT>
__global__ __launch_bounds__(256) void gemm_mfma(const float* __restrict__ A,
                                                 const ushort* __restrict__ Bt,
                                                 OutT* __restrict__ C,
                                                 int M, int N, int ldc) {
    __shared__ ushort As[128 * 64];   // 16 KB, swizzled rows of 64 ushorts (128B)
    __shared__ ushort Bs[128 * 64];   // 16 KB
    int t = threadIdx.x;
    int n0 = blockIdx.x * 128;        // n-inner: 4 n-tiles share an A m-tile in L2
    int m0 = blockIdx.y * 128;

    int srow = t >> 3;                     // 0..31
    int kbx  = (t & 7) ^ (srow & 7);       // involution within 8-row stripe

    int lane = t & 63;
    int wv   = t >> 6;
    int wr   = wv >> 1, wc = wv & 1;       // wave -> 64x64 quadrant
    int l15  = lane & 15, lhi = lane >> 4;

    f32x4 acc[4][4];
    #pragma unroll
    for (int m = 0; m < 4; m++)
        #pragma unroll
        for (int n = 0; n < 4; n++) acc[m][n] = (f32x4){0.f, 0.f, 0.f, 0.f};

    for (int kt = 0; kt < KP / 64; kt++) {
        int k0 = kt * 64;
        // ---- B staging: 4 rounds of global_load_lds (16B/lane) ----
        #pragma unroll
        for (int r = 0; r < 4; r++) {
            int row = r * 32 + srow;
            const ushort* gb = Bt + (size_t)(n0 + row) * KP + k0 + kbx * 8;
            ushort* lb = &Bs[(size_t)row * 64 + (t & 7) * 8];
            __builtin_amdgcn_global_load_lds(
                (const __attribute__((address_space(1))) unsigned int*)gb,
                (__attribute__((address_space(3))) unsigned int*)lb, 16, 0, 0);
        }
        // ---- A staging: f32 float4 loads -> bf16 -> swizzled ds_write ----
        #pragma unroll
        for (int r = 0; r < 8; r++) {
            int cid = r * 256 + t;            // 0..2047
            int row = cid >> 4;               // 0..127
            int c4  = cid & 15;               // float4 index in 64-col k-slab
            int gm = m0 + row, gk = k0 + c4 * 4;
            float4 a4 = make_float4(0.f, 0.f, 0.f, 0.f);
            if (gm < M && gk < FEAT) a4 = *(const float4*)&A[(size_t)gm * FEAT + gk];
            ushort4 h4;
            h4.x = f2bf(a4.x); h4.y = f2bf(a4.y); h4.z = f2bf(a4.z); h4.w = f2bf(a4.w);
            int slot = (c4 >> 1) ^ (row & 7);
            *(ushort4*)&As[(size_t)row * 64 + slot * 8 + (c4 & 1) * 4] = h4;
        }
        __syncthreads();

        #pragma unroll
        for (int ks = 0; ks < 2; ks++) {
            int cswz = ((ks * 64 + lhi * 16) ^ ((lane & 7) << 4)) >> 1;
            short8 af[4], bfr[4];
            #pragma unroll
            for (int m = 0; m < 4; m++) {
                int rowl = wr * 64 + m * 16 + l15;
                af[m] = *(const short8*)&As[rowl * 64 + cswz];
            }
            #pragma unroll
            for (int n = 0; n < 4; n++) {
                int rowl = wc * 64 + n * 16 + l15;
                bfr[n] = *(const short8*)&Bs[rowl * 64 + cswz];
            }
            #pragma unroll
            for (int m = 0; m < 4; m++)
                #pragma unroll
                for (int n = 0; n < 4; n++)
                    acc[m][n] = __builtin_amdgcn_mfma_f32_16x16x32_bf16(
                        af[m], bfr[n], acc[m][n], 0, 0, 0);
        }
        __syncthreads();
    }

    #pragma unroll
    for (int m = 0; m < 4; m++) {
        #pragma unroll
        for (int n = 0; n < 4; n++) {
            int gc = n0 + wc * 64 + n * 16 + l15;
            if (gc >= N) continue;
            int gr0 = m0 + wr * 64 + m * 16 + lhi * 4;
            #pragma unroll
            for (int j = 0; j < 4; j++) {
                int gr = gr0 + j;
                if (gr < M) {
                    if constexpr (sizeof(OutT) == 2)
                        C[(size_t)gr * ldc + gc] = (OutT)f2bf(acc[m][n][j]);
                    else
                        C[(size_t)gr * ldc + gc] = (OutT)acc[m][n][j];
                }
            }
        }
    }
}

// ---------------- big GCN: pull-gather (bf16 xw) + fused bias/relu -----------
__global__ __launch_bounds__(256) void gather_big(const int* __restrict__ esrc,
                                                  const float* __restrict__ ecoef,
                                                  const int* __restrict__ offs,
                                                  const int* __restrict__ cnt,
                                                  const ushort* __restrict__ xwb,
                                                  const float* __restrict__ dinv,
                                                  const float* __restrict__ b1,
                                                  float* __restrict__ x) {
    int wave = threadIdx.x >> 6, lane = threadIdx.x & 63;
    int dst = blockIdx.x * 4 + wave;
    if (dst >= N_NODES) return;
    int start = offs[dst], deg = cnt[dst];
    float acc[8] = {};
    for (int j = 0; j < deg; j++) {
        int src = esrc[start + j];
        float c = ecoef[start + j];
        const uint* rp = (const uint*)(xwb + (size_t)src * EMB);
        #pragma unroll
        for (int q = 0; q < 4; q++) {
            int k = lane + q * 64;           // uint index, 2 bf16 each
            if (k < EMB / 2) {
                uint u = rp[k];
                acc[2 * q]     += __uint_as_float(u << 16) * c;
                acc[2 * q + 1] += __uint_as_float(u & 0xffff0000u) * c;
            }
        }
    }
    float d2 = dinv[dst] * dinv[dst];
    const uint* sp = (const uint*)(xwb + (size_t)dst * EMB);
    float* xo = x + (size_t)dst * EMB;
    #pragma unroll
    for (int q = 0; q < 4; q++) {
        int k = lane + q * 64;
        if (k < EMB / 2) {
            uint u = sp[k];
            float s0 = acc[2 * q]     + __uint_as_float(u << 16) * d2 + b1[2 * k];
            float s1 = acc[2 * q + 1] + __uint_as_float(u & 0xffff0000u) * d2 + b1[2 * k + 1];
            *(float2*)&xo[2 * k] = make_float2(fmaxf(s0, 0.f), fmaxf(s1, 0.f));
        }
    }
}

// ---------------- temp = num_feature copy, then row replace ------------------
__global__ void copy_temp(const float* __restrict__ nf, float* __restrict__ temp) {
    size_t i = (size_t)blockIdx.x * blockDim.x + threadIdx.x;
    size_t stride = (size_t)gridDim.x * blockDim.x;
    const float4* src = (const float4*)nf;
    float4* dst = (float4*)temp;
    size_t n4 = (size_t)N_NODES * FEAT / 4;
    for (; i < n4; i += stride) dst[i] = src[i];
}
__global__ void set_rows(const float* __restrict__ x1s, const int* __restrict__ idxbuf,
                         float* __restrict__ temp) {
    int j = blockIdx.x, t = threadIdx.x;
    int r = idxbuf[j];
    for (int k = t; k < FEAT; k += 256)
        temp[(size_t)r * FEAT + k] = x1s[(size_t)(KTOP + j) * FEAT + k];
}

// ---------------- ConvE-ish scoring ------------------------------------------
__global__ void score_kernel(const float* __restrict__ ent, const float* __restrict__ rel,
                             const int* __restrict__ r_idx, const int* __restrict__ e1_idx,
                             const int* __restrict__ e2_idx, const float* __restrict__ conv_w,
                             const float* __restrict__ conv_b, const float* __restrict__ fc_w,
                             const float* __restrict__ fc_b, float* __restrict__ out) {
    __shared__ float cw[24];
    __shared__ float cb[8];
    int t = threadIdx.x;
    if (t < 24) cw[t] = conv_w[t];
    if (t < 8)  cb[t] = conv_b[t];
    __syncthreads();
    int wave = t >> 6, lane = t & 63;
    int b = blockIdx.x * 4 + wave;
    if (b >= BATCH) return;
    const float* r  = rel + (size_t)r_idx[b] * EMB;
    const float* e1 = ent + (size_t)e1_idx[b] * EMB;
    const float* e2 = ent + (size_t)e2_idx[b] * EMB;
    float partial = 0.f;
    for (int p = lane; p < EMB; p += 64) {
        float c0 = r[p], c1 = e1[p], c2 = e2[p];
        for (int g = 0; g < 4; g++) {
            float h0 = c0 * cw[(2 * g) * 3 + 0] + c1 * cw[(2 * g) * 3 + 1] + c2 * cw[(2 * g) * 3 + 2] + cb[2 * g];
            float h1 = c0 * cw[(2 * g + 1) * 3 + 0] + c1 * cw[(2 * g + 1) * 3 + 1] + c2 * cw[(2 * g + 1) * 3 + 2] + cb[2 * g + 1];
            partial += fmaxf(h0, h1) * fc_w[g * EMB + p];
        }
    }
    for (int off = 32; off > 0; off >>= 1) partial += __shfl_down(partial, off, 64);
    if (lane == 0) out[b] = partial + fc_b[0];
}

extern "C" void kernel_launch(void* const* d_in, const int* in_sizes, int n_in,
                              void* d_out, int out_size, void* d_ws, size_t ws_size,
                              hipStream_t stream) {
    const float* num_feature = (const float*)d_in[0];
    const float* anchor      = (const float*)d_in[1];
    const float* Wp          = (const float*)d_in[2];
    const float* bp          = (const float*)d_in[3];
    const float* Wa          = (const float*)d_in[4];
    const float* ba          = (const float*)d_in[5];
    const float* W1          = (const float*)d_in[6];
    const float* b1          = (const float*)d_in[7];
    const float* ent_emb     = (const float*)d_in[8];
    const float* rel_emb     = (const float*)d_in[9];
    const float* conv_w      = (const float*)d_in[10];
    const float* conv_b      = (const float*)d_in[11];
    const float* fc_w        = (const float*)d_in[12];
    const float* fc_b        = (const float*)d_in[13];
    const int*   edge_index  = (const int*)d_in[14];
    const int*   ra_edge     = (const int*)d_in[15];
    const int*   r_idx       = (const int*)d_in[16];
    const int*   e1_idx      = (const int*)d_in[17];
    const int*   e2_idx      = (const int*)d_in[18];

    float* out_score = (float*)d_out;                       // 4096
    float* out_x     = out_score + BATCH;                   // 50500*400
    float* out_temp  = out_x + (size_t)N_NODES * EMB;       // 50500*1000 floats

    // scratch carved out of the temp region (all consumed before copy_temp):
    float* base = out_temp;
    ushort* xwb   = (ushort*)base;                            // 20.2M ushorts (bf16 xw)
    ushort* Btbf  = (ushort*)(base + 10100000);               // NP*KP bf16
    ushort* Watbf = (ushort*)(base + 10100000 + 262144);      // KP*KP bf16
    int*   cnt      = (int*)(base + 10100000 + 262144 + 524288);
    int*   cursor   = cnt + N_NODES;
    int*   offs     = cursor + N_NODES;
    int*   partials = offs + N_NODES;
    int*   esrc     = partials + 256;
    float* ecoef    = (float*)(esrc + N_EDGES);               // ends ~11.84M < 50.5M

    float* ws_f    = (float*)d_ws;
    float* logits  = ws_f;                 // 512
    int*   idxbuf  = (int*)(ws_f + 512);   // 64
    float* probsel = ws_f + 576;           // 64
    float* dinv_s  = ws_f + 640;           // 128
    float* ra      = ws_f + 768;           // 100000
    float* raw     = ws_f + 100768;        // 100000
    float* x1s     = ws_f + 200768;        // 100000
    float* dinv    = ws_f + 300768;        // 50500  -> total 351268 floats

    hipMemsetAsync(d_ws, 0, 351268 * sizeof(float), stream);
    hipMemsetAsync(cnt, 0, 2 * N_NODES * sizeof(int), stream);   // cnt + cursor

    // ---- small GCN pipeline (gemm via MFMA, f32 A direct) ----
    logits_kernel<<<RELM1, 256, 0, stream>>>(num_feature, Wp, bp, logits);
    topk_kernel<<<1, 512, 0, stream>>>(logits, idxbuf, probsel);
    build_ra<<<2 * KTOP, 256, 0, stream>>>(anchor, num_feature, idxbuf, probsel, ra);
    transpose_bf16<<<dim3(16, 16), 256, 0, stream>>>(Wa, FEAT, FEAT, Watbf);
    gemm_mfma<float><<<dim3(8, 1), 256, 0, stream>>>(ra, Watbf, raw, 2 * KTOP, FEAT, FEAT);
    deg_kernel<<<8, 256, 0, stream>>>(ra_edge, 2000, dinv_s);
    dinv_kernel<<<1, 256, 0, stream>>>(dinv_s, 2 * KTOP);
    scatter_small<<<500, 256, 0, stream>>>(ra_edge, raw, dinv_s, x1s);
    finalize_small<<<2 * KTOP, 256, 0, stream>>>(raw, dinv_s, ba, x1s);

    // ---- big graph CSR build ----
    hist_kernel<<<(N_EDGES + 255) / 256, 256, 0, stream>>>(edge_index, cnt);
    dinv_from_cnt<<<NB_SCAN, 256, 0, stream>>>(cnt, dinv);
    scan_blocks<<<NB_SCAN, 256, 0, stream>>>(cnt, offs, partials);
    scan_carry<<<1, 256, 0, stream>>>(partials);
    scan_add<<<NB_SCAN, 256, 0, stream>>>(offs, partials);
    fill_csr<<<(N_EDGES + 255) / 256, 256, 0, stream>>>(edge_index, offs, cursor, dinv,
                                                        esrc, ecoef);

    // ---- big GEMM (bf16 MFMA, f32 A direct, bf16 out) ----
    transpose_bf16<<<dim3(16, 8), 256, 0, stream>>>(W1, FEAT, EMB, Btbf);
    gemm_mfma<ushort><<<dim3(NP / 128, MP / 128), 256, 0, stream>>>(num_feature, Btbf, xwb,
                                                                    N_NODES, EMB, EMB);

    // ---- aggregation (pull) with fused bias+relu ----
    gather_big<<<(N_NODES + 3) / 4, 256, 0, stream>>>(esrc, ecoef, offs, cnt, xwb, dinv,
                                                      b1, out_x);

    // ---- temp output ----
    copy_temp<<<4096, 256, 0, stream>>>(num_feature, out_temp);
    set_rows<<<KTOP, 256, 0, stream>>>(x1s, idxbuf, out_temp);

    // ---- scoring ----
    score_kernel<<<BATCH / 4, 256, 0, stream>>>(ent_emb, rel_emb, r_idx, e1_idx, e2_idx,
                                                conv_w, conv_b, fc_w, fc_b, out_score);
}

// Round 6
// 496.032 us; speedup vs baseline: 1.3770x; 1.3770x over previous
//
#include <hip/hip_runtime.h>
#include <hip/hip_bf16.h>

#define NUM_ENT   50000
#define NUM_RELC  500
#define KTOP      50
#define EMB       400
#define FEAT      1000
#define N_NODES   50500
#define N_EDGES   400000
#define BATCH     4096
#define RELM1     499     // NUM_REL - 1

// padded GEMM dims
#define KP   1024         // FEAT padded to mult of 64
#define MP   50560        // N_NODES padded to 395*128
#define NP   512          // EMB padded to mult of 128

#define NB_SCAN ((N_NODES + 255) / 256)   // 198

typedef __attribute__((ext_vector_type(8))) short short8;
typedef __attribute__((ext_vector_type(4))) float f32x4;

__device__ __forceinline__ ushort f2bf(float x) {
    __hip_bfloat16 h = __float2bfloat16(x);
    return *reinterpret_cast<ushort*>(&h);
}

// ---------------- logits: rel_feat @ Wp.T + bp  (499 dots of length 1000) ----
__global__ void logits_kernel(const float* __restrict__ nf, const float* __restrict__ Wp,
                              const float* __restrict__ bp, float* __restrict__ logits) {
    __shared__ float red[256];
    int i = blockIdx.x, t = threadIdx.x;
    float s = 0.f;
    for (int k = t; k < FEAT; k += 256) s += nf[(size_t)i * FEAT + k] * Wp[k];
    red[t] = s; __syncthreads();
    for (int st = 128; st > 0; st >>= 1) { if (t < st) red[t] += red[t + st]; __syncthreads(); }
    if (t == 0) logits[i] = red[0] + bp[0];
}

// ---------------- softmax over 499 + top-50 (sorted ascending) ---------------
__global__ void topk_kernel(const float* __restrict__ logits, int* __restrict__ idxbuf,
                            float* __restrict__ probsel) {
    __shared__ float l[RELM1];
    __shared__ float p[RELM1];
    __shared__ int   flag[RELM1];
    __shared__ float red[512];
    int t = threadIdx.x;  // 512 threads
    float v = (t < RELM1) ? logits[t] : -1e30f;
    if (t < RELM1) l[t] = v;
    red[t] = v; __syncthreads();
    for (int s = 256; s > 0; s >>= 1) { if (t < s) red[t] = fmaxf(red[t], red[t + s]); __syncthreads(); }
    float m = red[0]; __syncthreads();
    float e = (t < RELM1) ? expf(v - m) : 0.f;
    red[t] = e; __syncthreads();
    for (int s = 256; s > 0; s >>= 1) { if (t < s) red[t] += red[t + s]; __syncthreads(); }
    float denom = red[0];
    if (t < RELM1) p[t] = e / denom;
    __syncthreads();
    if (t < RELM1) {
        float lv = l[t]; int cnt = 0;
        for (int j = 0; j < RELM1; j++) {
            float lj = l[j];
            cnt += (lj > lv) || (lj == lv && j < t);
        }
        flag[t] = (cnt < KTOP);
    }
    __syncthreads();
    if (t == 0) {
        int n = 0;
        for (int i = 0; i < RELM1; i++)
            if (flag[i]) { idxbuf[n] = i; probsel[n] = p[i]; n++; }
    }
}

// ---------------- ra = concat(anchor, num_feature[idx]*prob[idx]) ------------
__global__ void build_ra(const float* __restrict__ anchor, const float* __restrict__ nf,
                         const int* __restrict__ idxbuf, const float* __restrict__ probsel,
                         float* __restrict__ ra) {
    int r = blockIdx.x, t = threadIdx.x;
    if (r < KTOP) {
        for (int k = t; k < FEAT; k += 256) ra[r * FEAT + k] = anchor[r * FEAT + k];
    } else {
        int j = r - KTOP; int src = idxbuf[j]; float pp = probsel[j];
        for (int k = t; k < FEAT; k += 256) ra[r * FEAT + k] = nf[(size_t)src * FEAT + k] * pp;
    }
}

// ---------------- degree + dinv (small graph, float path) --------------------
__global__ void deg_kernel(const int* __restrict__ ei, int nedges, float* __restrict__ deg) {
    int e = blockIdx.x * 256 + threadIdx.x;
    if (e < nedges) { int dst = ei[nedges + e]; atomicAdd(&deg[dst], 1.0f); }
}
__global__ void dinv_kernel(float* __restrict__ deg, int n) {
    int i = blockIdx.x * 256 + threadIdx.x;
    if (i < n) deg[i] = 1.0f / sqrtf(deg[i] + 1.0f);
}

// ---------------- small GCN scatter + finalize -------------------------------
__global__ void scatter_small(const int* __restrict__ ei, const float* __restrict__ raw,
                              const float* __restrict__ dinv_s, float* __restrict__ acc) {
    int wave = threadIdx.x >> 6, lane = threadIdx.x & 63;
    int e = blockIdx.x * 4 + wave;
    if (e >= 2000) return;
    int src = ei[e], dst = ei[2000 + e];
    float c = dinv_s[src] * dinv_s[dst];
    const float* rs = raw + (size_t)src * FEAT;
    float* ad = acc + (size_t)dst * FEAT;
    for (int k = lane; k < FEAT; k += 64) atomicAdd(&ad[k], rs[k] * c);
}
__global__ void finalize_small(const float* __restrict__ raw, const float* __restrict__ dinv_s,
                               const float* __restrict__ ba, float* __restrict__ x1s) {
    int r = blockIdx.x, t = threadIdx.x;
    float d2 = dinv_s[r] * dinv_s[r];
    for (int k = t; k < FEAT; k += 256) {
        float v = x1s[r * FEAT + k] + raw[r * FEAT + k] * d2 + ba[k];
        x1s[r * FEAT + k] = fmaxf(v, 0.f);
    }
}

// ---------------- big graph: CSR build ---------------------------------------
__global__ void hist_kernel(const int* __restrict__ ei, int* __restrict__ cnt) {
    int e = blockIdx.x * 256 + threadIdx.x;
    if (e < N_EDGES) atomicAdd(&cnt[ei[N_EDGES + e]], 1);
}
__global__ void dinv_from_cnt(const int* __restrict__ cnt, float* __restrict__ dinv) {
    int i = blockIdx.x * 256 + threadIdx.x;
    if (i < N_NODES) dinv[i] = rsqrtf((float)cnt[i] + 1.0f);
}
__global__ void scan_blocks(const int* __restrict__ cnt, int* __restrict__ offs,
                            int* __restrict__ partials) {
    __shared__ int s[256];
    int b = blockIdx.x, t = threadIdx.x;
    int i = b * 256 + t;
    int v = (i < N_NODES) ? cnt[i] : 0;
    s[t] = v; __syncthreads();
    for (int off = 1; off < 256; off <<= 1) {
        int add = (t >= off) ? s[t - off] : 0;
        __syncthreads();
        s[t] += add;
        __syncthreads();
    }
    if (i < N_NODES) offs[i] = s[t] - v;   // exclusive scan within block
    if (t == 255) partials[b] = s[t];
}
__global__ void scan_carry(int* __restrict__ partials) {
    __shared__ int s[256];
    int t = threadIdx.x;
    int v = (t < NB_SCAN) ? partials[t] : 0;
    s[t] = v; __syncthreads();
    for (int off = 1; off < 256; off <<= 1) {
        int add = (t >= off) ? s[t - off] : 0;
        __syncthreads();
        s[t] += add;
        __syncthreads();
    }
    if (t < NB_SCAN) partials[t] = s[t] - v;   // exclusive
}
__global__ void scan_add(int* __restrict__ offs, const int* __restrict__ partials) {
    int b = blockIdx.x; int i = b * 256 + threadIdx.x;
    if (i < N_NODES) offs[i] += partials[b];
}
__global__ void fill_csr(const int* __restrict__ ei, const int* __restrict__ offs,
                         int* __restrict__ cursor, const float* __restrict__ dinv,
                         int* __restrict__ esrc, float* __restrict__ ecoef) {
    int e = blockIdx.x * 256 + threadIdx.x;
    if (e >= N_EDGES) return;
    int src = ei[e], dst = ei[N_EDGES + e];
    int pos = offs[dst] + atomicAdd(&cursor[dst], 1);
    esrc[pos] = src;
    ecoef[pos] = dinv[src] * dinv[dst];
}

// ---------------- bf16 conversion: A = num_feature -> [MP][KP] bf16 ----------
__global__ void convertA(const float* __restrict__ nf, ushort* __restrict__ Abf) {
    size_t idx = (size_t)blockIdx.x * 256 + threadIdx.x;
    size_t stride = (size_t)gridDim.x * 256;
    size_t total = (size_t)MP * KP / 8;     // 8 bf16 per thread-chunk
    for (; idx < total; idx += stride) {
        int row = (int)(idx >> 7);          // KP/8 = 128 chunks per row
        int kb  = (int)(idx & 127);
        ushort v[8];
        if (row < N_NODES && kb < 125) {    // 125*8 = 1000 = FEAT
            const float* src = nf + (size_t)row * FEAT + kb * 8;
            #pragma unroll
            for (int j = 0; j < 8; j++) v[j] = f2bf(src[j]);
        } else {
            #pragma unroll
            for (int j = 0; j < 8; j++) v[j] = 0;
        }
        *(uint4*)&Abf[idx * 8] = *(uint4*)v;
    }
}

// ---------------- ra (100x1000 f32) -> rabf [128][KP] bf16 -------------------
__global__ void convert_rabf(const float* __restrict__ ra, ushort* __restrict__ rabf) {
    int idx = blockIdx.x * 256 + threadIdx.x;   // 128*KP/8 = 16384 chunks
    if (idx >= 128 * KP / 8) return;
    int row = idx >> 7;
    int kb  = idx & 127;
    ushort v[8];
    if (row < 2 * KTOP && kb < 125) {
        const float* src = ra + (size_t)row * FEAT + kb * 8;
        #pragma unroll
        for (int j = 0; j < 8; j++) v[j] = f2bf(src[j]);
    } else {
        #pragma unroll
        for (int j = 0; j < 8; j++) v[j] = 0;
    }
    *(uint4*)&rabf[idx * 8] = *(uint4*)v;
}

// ---------------- LDS-tiled transpose-convert: dst[n][KP] = bf16(src[k][n]) --
__global__ void transpose_bf16(const float* __restrict__ src, int K, int N,
                               ushort* __restrict__ dst) {
    __shared__ float tile[64][65];
    int k0 = blockIdx.x * 64, n0 = blockIdx.y * 64;
    int tx = threadIdx.x & 63, ty = threadIdx.x >> 6;   // 64 x 4
    for (int i = ty; i < 64; i += 4) {
        int k = k0 + i, n = n0 + tx;
        tile[i][tx] = (k < K && n < N) ? src[(size_t)k * N + n] : 0.f;
    }
    __syncthreads();
    for (int i = ty; i < 64; i += 4) {
        int n = n0 + i, k = k0 + tx;
        dst[(size_t)n * KP + k] = f2bf(tile[tx][i]);
    }
}

// ---------------- MFMA GEMM: C[M][ldc] = A(bf16,[*][KP]) @ Bt(bf16,[*][KP])^T
// 128x128 tile, BK=64, 4 waves (2x2), global_load_lds + XOR-swizzled LDS.
template <typename OutT>
__global__ __launch_bounds__(256) void gemm_mfma(const ushort* __restrict__ A,
                                                 const ushort* __restrict__ Bt,
                                                 OutT* __restrict__ C,
                                                 int M, int N, int ldc) {
    __shared__ ushort As[128 * 64];   // 16 KB, swizzled rows of 64 ushorts (128B)
    __shared__ ushort Bs[128 * 64];   // 16 KB
    int t = threadIdx.x;
    int m0 = blockIdx.x * 128;
    int n0 = blockIdx.y * 128;

    int srow = t >> 3;                     // 0..31
    int kbx  = (t & 7) ^ (srow & 7);       // involution within 8-row stripe

    int lane = t & 63;
    int wv   = t >> 6;
    int wr   = wv >> 1, wc = wv & 1;       // wave -> 64x64 quadrant
    int l15  = lane & 15, lhi = lane >> 4;

    f32x4 acc[4][4];
    #pragma unroll
    for (int m = 0; m < 4; m++)
        #pragma unroll
        for (int n = 0; n < 4; n++) acc[m][n] = (f32x4){0.f, 0.f, 0.f, 0.f};

    for (int kt = 0; kt < KP / 64; kt++) {
        int k0 = kt * 64;
        #pragma unroll
        for (int r = 0; r < 4; r++) {
            int row = r * 32 + srow;
            const ushort* ga = A  + (size_t)(m0 + row) * KP + k0 + kbx * 8;
            const ushort* gb = Bt + (size_t)(n0 + row) * KP + k0 + kbx * 8;
            ushort* la = &As[(size_t)row * 64 + (t & 7) * 8];
            ushort* lb = &Bs[(size_t)row * 64 + (t & 7) * 8];
            __builtin_amdgcn_global_load_lds(
                (const __attribute__((address_space(1))) unsigned int*)ga,
                (__attribute__((address_space(3))) unsigned int*)la, 16, 0, 0);
            __builtin_amdgcn_global_load_lds(
                (const __attribute__((address_space(1))) unsigned int*)gb,
                (__attribute__((address_space(3))) unsigned int*)lb, 16, 0, 0);
        }
        __syncthreads();

        #pragma unroll
        for (int ks = 0; ks < 2; ks++) {
            int cswz = ((ks * 64 + lhi * 16) ^ ((lane & 7) << 4)) >> 1;
            short8 af[4], bfr[4];
            #pragma unroll
            for (int m = 0; m < 4; m++) {
                int rowl = wr * 64 + m * 16 + l15;
                af[m] = *(const short8*)&As[rowl * 64 + cswz];
            }
            #pragma unroll
            for (int n = 0; n < 4; n++) {
                int rowl = wc * 64 + n * 16 + l15;
                bfr[n] = *(const short8*)&Bs[rowl * 64 + cswz];
            }
            #pragma unroll
            for (int m = 0; m < 4; m++)
                #pragma unroll
                for (int n = 0; n < 4; n++)
                    acc[m][n] = __builtin_amdgcn_mfma_f32_16x16x32_bf16(
                        af[m], bfr[n], acc[m][n], 0, 0, 0);
        }
        __syncthreads();
    }

    #pragma unroll
    for (int m = 0; m < 4; m++) {
        #pragma unroll
        for (int n = 0; n < 4; n++) {
            int gc = n0 + wc * 64 + n * 16 + l15;
            if (gc >= N) continue;
            int gr0 = m0 + wr * 64 + m * 16 + lhi * 4;
            #pragma unroll
            for (int j = 0; j < 4; j++) {
                int gr = gr0 + j;
                if (gr < M) {
                    if constexpr (sizeof(OutT) == 2)
                        C[(size_t)gr * ldc + gc] = (OutT)f2bf(acc[m][n][j]);
                    else
                        C[(size_t)gr * ldc + gc] = (OutT)acc[m][n][j];
                }
            }
        }
    }
}

// ---------------- big GCN: pull-gather (bf16 xw) + fused bias/relu -----------
__global__ __launch_bounds__(256) void gather_big(const int* __restrict__ esrc,
                                                  const float* __restrict__ ecoef,
                                                  const int* __restrict__ offs,
                                                  const int* __restrict__ cnt,
                                                  const ushort* __restrict__ xwb,
                                                  const float* __restrict__ dinv,
                                                  const float* __restrict__ b1,
                                                  float* __restrict__ x) {
    int wave = threadIdx.x >> 6, lane = threadIdx.x & 63;
    int dst = blockIdx.x * 4 + wave;
    if (dst >= N_NODES) return;
    int start = offs[dst], deg = cnt[dst];
    float acc[8] = {};
    for (int j = 0; j < deg; j++) {
        int src = esrc[start + j];
        float c = ecoef[start + j];
        const uint* rp = (const uint*)(xwb + (size_t)src * EMB);
        #pragma unroll
        for (int q = 0; q < 4; q++) {
            int k = lane + q * 64;           // uint index, 2 bf16 each
            if (k < EMB / 2) {
                uint u = rp[k];
                acc[2 * q]     += __uint_as_float(u << 16) * c;
                acc[2 * q + 1] += __uint_as_float(u & 0xffff0000u) * c;
            }
        }
    }
    float d2 = dinv[dst] * dinv[dst];
    const uint* sp = (const uint*)(xwb + (size_t)dst * EMB);
    float* xo = x + (size_t)dst * EMB;
    #pragma unroll
    for (int q = 0; q < 4; q++) {
        int k = lane + q * 64;
        if (k < EMB / 2) {
            uint u = sp[k];
            float s0 = acc[2 * q]     + __uint_as_float(u << 16) * d2 + b1[2 * k];
            float s1 = acc[2 * q + 1] + __uint_as_float(u & 0xffff0000u) * d2 + b1[2 * k + 1];
            *(float2*)&xo[2 * k] = make_float2(fmaxf(s0, 0.f), fmaxf(s1, 0.f));
        }
    }
}

// ---------------- temp = num_feature copy, then row replace ------------------
__global__ void copy_temp(const float* __restrict__ nf, float* __restrict__ temp) {
    size_t i = (size_t)blockIdx.x * blockDim.x + threadIdx.x;
    size_t stride = (size_t)gridDim.x * blockDim.x;
    const float4* src = (const float4*)nf;
    float4* dst = (float4*)temp;
    size_t n4 = (size_t)N_NODES * FEAT / 4;
    for (; i < n4; i += stride) dst[i] = src[i];
}
__global__ void set_rows(const float* __restrict__ x1s, const int* __restrict__ idxbuf,
                         float* __restrict__ temp) {
    int j = blockIdx.x, t = threadIdx.x;
    int r = idxbuf[j];
    for (int k = t; k < FEAT; k += 256)
        temp[(size_t)r * FEAT + k] = x1s[(size_t)(KTOP + j) * FEAT + k];
}

// ---------------- ConvE-ish scoring ------------------------------------------
__global__ void score_kernel(const float* __restrict__ ent, const float* __restrict__ rel,
                             const int* __restrict__ r_idx, const int* __restrict__ e1_idx,
                             const int* __restrict__ e2_idx, const float* __restrict__ conv_w,
                             const float* __restrict__ conv_b, const float* __restrict__ fc_w,
                             const float* __restrict__ fc_b, float* __restrict__ out) {
    __shared__ float cw[24];
    __shared__ float cb[8];
    int t = threadIdx.x;
    if (t < 24) cw[t] = conv_w[t];
    if (t < 8)  cb[t] = conv_b[t];
    __syncthreads();
    int wave = t >> 6, lane = t & 63;
    int b = blockIdx.x * 4 + wave;
    if (b >= BATCH) return;
    const float* r  = rel + (size_t)r_idx[b] * EMB;
    const float* e1 = ent + (size_t)e1_idx[b] * EMB;
    const float* e2 = ent + (size_t)e2_idx[b] * EMB;
    float partial = 0.f;
    for (int p = lane; p < EMB; p += 64) {
        float c0 = r[p], c1 = e1[p], c2 = e2[p];
        for (int g = 0; g < 4; g++) {
            float h0 = c0 * cw[(2 * g) * 3 + 0] + c1 * cw[(2 * g) * 3 + 1] + c2 * cw[(2 * g) * 3 + 2] + cb[2 * g];
            float h1 = c0 * cw[(2 * g + 1) * 3 + 0] + c1 * cw[(2 * g + 1) * 3 + 1] + c2 * cw[(2 * g + 1) * 3 + 2] + cb[2 * g + 1];
            partial += fmaxf(h0, h1) * fc_w[g * EMB + p];
        }
    }
    for (int off = 32; off > 0; off >>= 1) partial += __shfl_down(partial, off, 64);
    if (lane == 0) out[b] = partial + fc_b[0];
}

extern "C" void kernel_launch(void* const* d_in, const int* in_sizes, int n_in,
                              void* d_out, int out_size, void* d_ws, size_t ws_size,
                              hipStream_t stream) {
    const float* num_feature = (const float*)d_in[0];
    const float* anchor      = (const float*)d_in[1];
    const float* Wp          = (const float*)d_in[2];
    const float* bp          = (const float*)d_in[3];
    const float* Wa          = (const float*)d_in[4];
    const float* ba          = (const float*)d_in[5];
    const float* W1          = (const float*)d_in[6];
    const float* b1          = (const float*)d_in[7];
    const float* ent_emb     = (const float*)d_in[8];
    const float* rel_emb     = (const float*)d_in[9];
    const float* conv_w      = (const float*)d_in[10];
    const float* conv_b      = (const float*)d_in[11];
    const float* fc_w        = (const float*)d_in[12];
    const float* fc_b        = (const float*)d_in[13];
    const int*   edge_index  = (const int*)d_in[14];
    const int*   ra_edge     = (const int*)d_in[15];
    const int*   r_idx       = (const int*)d_in[16];
    const int*   e1_idx      = (const int*)d_in[17];
    const int*   e2_idx      = (const int*)d_in[18];

    float* out_score = (float*)d_out;                       // 4096
    float* out_x     = out_score + BATCH;                   // 50500*400
    float* out_temp  = out_x + (size_t)N_NODES * EMB;       // 50500*1000 floats

    // scratch carved out of the temp region (all consumed before copy_temp):
    float* base = out_temp;
    ushort* Abf   = (ushort*)base;                           // 25,886,720 floats
    ushort* xwb   = (ushort*)(base + 25886720);              // 10,100,000 floats
    ushort* Btbf  = (ushort*)(base + 35986720);              //    262,144 floats
    ushort* Watbf = (ushort*)(base + 36248864);              //    524,288 floats
    ushort* rabf  = (ushort*)(base + 36773152);              //     65,536 floats
    int*   cnt      = (int*)(base + 36838688);
    int*   cursor   = cnt + N_NODES;
    int*   offs     = cursor + N_NODES;
    int*   partials = offs + N_NODES;
    int*   esrc     = partials + 256;
    float* ecoef    = (float*)(esrc + N_EDGES);              // ends ~37.8M < 50.5M

    float* ws_f    = (float*)d_ws;
    float* logits  = ws_f;                 // 512
    int*   idxbuf  = (int*)(ws_f + 512);   // 64
    float* probsel = ws_f + 576;           // 64
    float* dinv_s  = ws_f + 640;           // 128
    float* ra      = ws_f + 768;           // 100000
    float* raw     = ws_f + 100768;        // 100000
    float* x1s     = ws_f + 200768;        // 100000
    float* dinv    = ws_f + 300768;        // 50500  -> total 351268 floats

    hipMemsetAsync(d_ws, 0, 351268 * sizeof(float), stream);
    hipMemsetAsync(cnt, 0, 2 * N_NODES * sizeof(int), stream);   // cnt + cursor

    // ---- small GCN pipeline (gemm via MFMA) ----
    logits_kernel<<<RELM1, 256, 0, stream>>>(num_feature, Wp, bp, logits);
    topk_kernel<<<1, 512, 0, stream>>>(logits, idxbuf, probsel);
    build_ra<<<2 * KTOP, 256, 0, stream>>>(anchor, num_feature, idxbuf, probsel, ra);
    transpose_bf16<<<dim3(16, 16), 256, 0, stream>>>(Wa, FEAT, FEAT, Watbf);
    convert_rabf<<<64, 256, 0, stream>>>(ra, rabf);
    gemm_mfma<float><<<dim3(1, 8), 256, 0, stream>>>(rabf, Watbf, raw, 2 * KTOP, FEAT, FEAT);
    deg_kernel<<<8, 256, 0, stream>>>(ra_edge, 2000, dinv_s);
    dinv_kernel<<<1, 256, 0, stream>>>(dinv_s, 2 * KTOP);
    scatter_small<<<500, 256, 0, stream>>>(ra_edge, raw, dinv_s, x1s);
    finalize_small<<<2 * KTOP, 256, 0, stream>>>(raw, dinv_s, ba, x1s);

    // ---- big graph CSR build ----
    hist_kernel<<<(N_EDGES + 255) / 256, 256, 0, stream>>>(edge_index, cnt);
    dinv_from_cnt<<<NB_SCAN, 256, 0, stream>>>(cnt, dinv);
    scan_blocks<<<NB_SCAN, 256, 0, stream>>>(cnt, offs, partials);
    scan_carry<<<1, 256, 0, stream>>>(partials);
    scan_add<<<NB_SCAN, 256, 0, stream>>>(offs, partials);
    fill_csr<<<(N_EDGES + 255) / 256, 256, 0, stream>>>(edge_index, offs, cursor, dinv,
                                                        esrc, ecoef);

    // ---- big GEMM (bf16 MFMA, bf16 A staged, bf16 out) ----
    convertA<<<4096, 256, 0, stream>>>(num_feature, Abf);
    transpose_bf16<<<dim3(16, 8), 256, 0, stream>>>(W1, FEAT, EMB, Btbf);
    gemm_mfma<ushort><<<dim3(MP / 128, NP / 128), 256, 0, stream>>>(Abf, Btbf, xwb,
                                                                    N_NODES, EMB, EMB);

    // ---- aggregation (pull) with fused bias+relu ----
    gather_big<<<(N_NODES + 3) / 4, 256, 0, stream>>>(esrc, ecoef, offs, cnt, xwb, dinv,
                                                      b1, out_x);

    // ---- temp output ----
    copy_temp<<<4096, 256, 0, stream>>>(num_feature, out_temp);
    set_rows<<<KTOP, 256, 0, stream>>>(x1s, idxbuf, out_temp);

    // ---- scoring ----
    score_kernel<<<BATCH / 4, 256, 0, stream>>>(ent_emb, rel_emb, r_idx, e1_idx, e2_idx,
                                                conv_w, conv_b, fc_w, fc_b, out_score);
}

// Round 7
// 490.524 us; speedup vs baseline: 1.3924x; 1.0112x over previous
//
#include <hip/hip_runtime.h>
#include <hip/hip_bf16.h>

#define NUM_ENT   50000
#define NUM_RELC  500
#define KTOP      50
#define EMB       400
#define FEAT      1000
#define N_NODES   50500
#define N_EDGES   400000
#define BATCH     4096
#define RELM1     499     // NUM_REL - 1

// padded GEMM dims
#define KP   1024         // FEAT padded to mult of 64
#define MP   50560        // N_NODES padded to 395*128
#define NP   512          // EMB padded to mult of 128

#define NB_SCAN ((N_NODES + 255) / 256)   // 198

typedef __attribute__((ext_vector_type(8))) short short8;
typedef __attribute__((ext_vector_type(4))) float f32x4;

__device__ __forceinline__ ushort f2bf(float x) {
    __hip_bfloat16 h = __float2bfloat16(x);
    return *reinterpret_cast<ushort*>(&h);
}

// ---------------- fused: temp = num_feature (f32) AND Abf = bf16(nf) padded --
__global__ void copy_convert(const float* __restrict__ nf, float* __restrict__ temp,
                             ushort* __restrict__ Abf) {
    size_t idx = (size_t)blockIdx.x * 256 + threadIdx.x;
    size_t stride = (size_t)gridDim.x * 256;
    size_t total = (size_t)MP * KP / 8;     // 8 elems per chunk
    for (; idx < total; idx += stride) {
        int row = (int)(idx >> 7);          // KP/8 = 128 chunks per row
        int kb  = (int)(idx & 127);
        if (row < N_NODES && kb < 125) {    // 125*8 = 1000 = FEAT
            size_t off = (size_t)row * FEAT + kb * 8;
            float4 a = *(const float4*)&nf[off];
            float4 b = *(const float4*)&nf[off + 4];
            *(float4*)&temp[off]     = a;
            *(float4*)&temp[off + 4] = b;
            ushort v[8];
            v[0] = f2bf(a.x); v[1] = f2bf(a.y); v[2] = f2bf(a.z); v[3] = f2bf(a.w);
            v[4] = f2bf(b.x); v[5] = f2bf(b.y); v[6] = f2bf(b.z); v[7] = f2bf(b.w);
            *(uint4*)&Abf[idx * 8] = *(uint4*)v;
        } else {
            uint4 z = {0u, 0u, 0u, 0u};
            *(uint4*)&Abf[idx * 8] = z;
        }
    }
}

// ---------------- logits: rel_feat @ Wp.T + bp  (499 dots of length 1000) ----
__global__ void logits_kernel(const float* __restrict__ nf, const float* __restrict__ Wp,
                              const float* __restrict__ bp, float* __restrict__ logits) {
    __shared__ float red[256];
    int i = blockIdx.x, t = threadIdx.x;
    float s = 0.f;
    for (int k = t; k < FEAT; k += 256) s += nf[(size_t)i * FEAT + k] * Wp[k];
    red[t] = s; __syncthreads();
    for (int st = 128; st > 0; st >>= 1) { if (t < st) red[t] += red[t + st]; __syncthreads(); }
    if (t == 0) logits[i] = red[0] + bp[0];
}

// ---------------- softmax over 499 + top-50 (sorted ascending) ---------------
__global__ void topk_kernel(const float* __restrict__ logits, int* __restrict__ idxbuf,
                            float* __restrict__ probsel) {
    __shared__ float l[RELM1];
    __shared__ float p[RELM1];
    __shared__ int   flag[RELM1];
    __shared__ float red[512];
    int t = threadIdx.x;  // 512 threads
    float v = (t < RELM1) ? logits[t] : -1e30f;
    if (t < RELM1) l[t] = v;
    red[t] = v; __syncthreads();
    for (int s = 256; s > 0; s >>= 1) { if (t < s) red[t] = fmaxf(red[t], red[t + s]); __syncthreads(); }
    float m = red[0]; __syncthreads();
    float e = (t < RELM1) ? expf(v - m) : 0.f;
    red[t] = e; __syncthreads();
    for (int s = 256; s > 0; s >>= 1) { if (t < s) red[t] += red[t + s]; __syncthreads(); }
    float denom = red[0];
    if (t < RELM1) p[t] = e / denom;
    __syncthreads();
    if (t < RELM1) {
        float lv = l[t]; int cnt = 0;
        for (int j = 0; j < RELM1; j++) {
            float lj = l[j];
            cnt += (lj > lv) || (lj == lv && j < t);
        }
        flag[t] = (cnt < KTOP);
    }
    __syncthreads();
    if (t == 0) {
        int n = 0;
        for (int i = 0; i < RELM1; i++)
            if (flag[i]) { idxbuf[n] = i; probsel[n] = p[i]; n++; }
    }
}

// ---------------- rabf[128][KP] = bf16(concat(anchor, nf[idx]*prob)) ---------
__global__ void build_rabf(const float* __restrict__ anchor, const float* __restrict__ nf,
                           const int* __restrict__ idxbuf, const float* __restrict__ probsel,
                           ushort* __restrict__ rabf) {
    int r = blockIdx.x, t = threadIdx.x;    // 128 blocks x 256
    const float* src = nullptr; float scale = 1.f;
    if (r < KTOP) {
        src = anchor + (size_t)r * FEAT;
    } else if (r < 2 * KTOP) {
        int j = r - KTOP;
        src = nf + (size_t)idxbuf[j] * FEAT;
        scale = probsel[j];
    }
    for (int k = t; k < KP; k += 256) {
        float v = (src != nullptr && k < FEAT) ? src[k] * scale : 0.f;
        rabf[(size_t)r * KP + k] = f2bf(v);
    }
}

// ---------------- small graph: fused degree+dinv (single block) --------------
__global__ void small_deg_dinv(const int* __restrict__ ei, float* __restrict__ dinv_s) {
    __shared__ int c[128];
    int t = threadIdx.x;
    if (t < 128) c[t] = 0;
    __syncthreads();
    for (int e = t; e < 2000; e += 256) atomicAdd(&c[ei[2000 + e]], 1);
    __syncthreads();
    if (t < 2 * KTOP) dinv_s[t] = rsqrtf((float)c[t] + 1.0f);
}

// ---------------- small GCN scatter + finalize -------------------------------
__global__ void scatter_small(const int* __restrict__ ei, const float* __restrict__ raw,
                              const float* __restrict__ dinv_s, float* __restrict__ acc) {
    int wave = threadIdx.x >> 6, lane = threadIdx.x & 63;
    int e = blockIdx.x * 4 + wave;
    if (e >= 2000) return;
    int src = ei[e], dst = ei[2000 + e];
    float c = dinv_s[src] * dinv_s[dst];
    const float* rs = raw + (size_t)src * FEAT;
    float* ad = acc + (size_t)dst * FEAT;
    for (int k = lane; k < FEAT; k += 64) atomicAdd(&ad[k], rs[k] * c);
}
__global__ void finalize_small(const float* __restrict__ raw, const float* __restrict__ dinv_s,
                               const float* __restrict__ ba, float* __restrict__ x1s) {
    int r = blockIdx.x, t = threadIdx.x;
    float d2 = dinv_s[r] * dinv_s[r];
    for (int k = t; k < FEAT; k += 256) {
        float v = x1s[r * FEAT + k] + raw[r * FEAT + k] * d2 + ba[k];
        x1s[r * FEAT + k] = fmaxf(v, 0.f);
    }
}

// ---------------- big graph: CSR build ---------------------------------------
__global__ void hist_kernel(const int* __restrict__ ei, int* __restrict__ cnt) {
    int e = blockIdx.x * 256 + threadIdx.x;
    if (e < N_EDGES) atomicAdd(&cnt[ei[N_EDGES + e]], 1);
}
__global__ void scan_blocks(const int* __restrict__ cnt, int* __restrict__ offs,
                            int* __restrict__ partials, float* __restrict__ dinv) {
    __shared__ int s[256];
    int b = blockIdx.x, t = threadIdx.x;
    int i = b * 256 + t;
    int v = (i < N_NODES) ? cnt[i] : 0;
    if (i < N_NODES) dinv[i] = rsqrtf((float)v + 1.0f);   // fused dinv
    s[t] = v; __syncthreads();
    for (int off = 1; off < 256; off <<= 1) {
        int add = (t >= off) ? s[t - off] : 0;
        __syncthreads();
        s[t] += add;
        __syncthreads();
    }
    if (i < N_NODES) offs[i] = s[t] - v;   // exclusive scan within block
    if (t == 255) partials[b] = s[t];
}
__global__ void scan_carry(int* __restrict__ partials) {
    __shared__ int s[256];
    int t = threadIdx.x;
    int v = (t < NB_SCAN) ? partials[t] : 0;
    s[t] = v; __syncthreads();
    for (int off = 1; off < 256; off <<= 1) {
        int add = (t >= off) ? s[t - off] : 0;
        __syncthreads();
        s[t] += add;
        __syncthreads();
    }
    if (t < NB_SCAN) partials[t] = s[t] - v;   // exclusive
}
__global__ void scan_add(int* __restrict__ offs, const int* __restrict__ partials) {
    int b = blockIdx.x; int i = b * 256 + threadIdx.x;
    if (i < N_NODES) offs[i] += partials[b];
}
__global__ void fill_csr(const int* __restrict__ ei, const int* __restrict__ offs,
                         int* __restrict__ cursor, const float* __restrict__ dinv,
                         int* __restrict__ esrc, float* __restrict__ ecoef) {
    int e = blockIdx.x * 256 + threadIdx.x;
    if (e >= N_EDGES) return;
    int src = ei[e], dst = ei[N_EDGES + e];
    int pos = offs[dst] + atomicAdd(&cursor[dst], 1);
    esrc[pos] = src;
    ecoef[pos] = dinv[src] * dinv[dst];
}

// ---------------- LDS-tiled transpose-convert: dst[n][KP] = bf16(src[k][n]) --
__global__ void transpose_bf16(const float* __restrict__ src, int K, int N,
                               ushort* __restrict__ dst) {
    __shared__ float tile[64][65];
    int k0 = blockIdx.x * 64, n0 = blockIdx.y * 64;
    int tx = threadIdx.x & 63, ty = threadIdx.x >> 6;   // 64 x 4
    for (int i = ty; i < 64; i += 4) {
        int k = k0 + i, n = n0 + tx;
        tile[i][tx] = (k < K && n < N) ? src[(size_t)k * N + n] : 0.f;
    }
    __syncthreads();
    for (int i = ty; i < 64; i += 4) {
        int n = n0 + i, k = k0 + tx;
        dst[(size_t)n * KP + k] = f2bf(tile[tx][i]);
    }
}

// ---------------- MFMA GEMM: C[M][ldc] = A(bf16,[*][KP]) @ Bt(bf16,[*][KP])^T
// 128x128 tile, BK=64, 4 waves (2x2), global_load_lds + XOR-swizzled LDS.
// n-frags with column base >= N are pruned (wave-uniform) to skip padded work.
template <typename OutT>
__global__ __launch_bounds__(256) void gemm_mfma(const ushort* __restrict__ A,
                                                 const ushort* __restrict__ Bt,
                                                 OutT* __restrict__ C,
                                                 int M, int N, int ldc) {
    __shared__ ushort As[128 * 64];   // 16 KB, swizzled rows of 64 ushorts (128B)
    __shared__ ushort Bs[128 * 64];   // 16 KB
    int t = threadIdx.x;
    int m0 = blockIdx.x * 128;
    int n0 = blockIdx.y * 128;

    int srow = t >> 3;                     // 0..31
    int kbx  = (t & 7) ^ (srow & 7);       // involution within 8-row stripe

    int lane = t & 63;
    int wv   = t >> 6;
    int wr   = wv >> 1, wc = wv & 1;       // wave -> 64x64 quadrant
    int l15  = lane & 15, lhi = lane >> 4;

    f32x4 acc[4][4];
    #pragma unroll
    for (int m = 0; m < 4; m++)
        #pragma unroll
        for (int n = 0; n < 4; n++) acc[m][n] = (f32x4){0.f, 0.f, 0.f, 0.f};

    for (int kt = 0; kt < KP / 64; kt++) {
        int k0 = kt * 64;
        #pragma unroll
        for (int r = 0; r < 4; r++) {
            int row = r * 32 + srow;
            const ushort* ga = A  + (size_t)(m0 + row) * KP + k0 + kbx * 8;
            const ushort* gb = Bt + (size_t)(n0 + row) * KP + k0 + kbx * 8;
            ushort* la = &As[(size_t)row * 64 + (t & 7) * 8];
            ushort* lb = &Bs[(size_t)row * 64 + (t & 7) * 8];
            __builtin_amdgcn_global_load_lds(
                (const __attribute__((address_space(1))) unsigned int*)ga,
                (__attribute__((address_space(3))) unsigned int*)la, 16, 0, 0);
            __builtin_amdgcn_global_load_lds(
                (const __attribute__((address_space(1))) unsigned int*)gb,
                (__attribute__((address_space(3))) unsigned int*)lb, 16, 0, 0);
        }
        __syncthreads();

        #pragma unroll
        for (int ks = 0; ks < 2; ks++) {
            int cswz = ((ks * 64 + lhi * 16) ^ ((lane & 7) << 4)) >> 1;
            short8 af[4], bfr[4];
            #pragma unroll
            for (int m = 0; m < 4; m++) {
                int rowl = wr * 64 + m * 16 + l15;
                af[m] = *(const short8*)&As[rowl * 64 + cswz];
            }
            #pragma unroll
            for (int n = 0; n < 4; n++) {
                if (n0 + wc * 64 + n * 16 < N) {          // prune padded n-frags
                    int rowl = wc * 64 + n * 16 + l15;
                    bfr[n] = *(const short8*)&Bs[rowl * 64 + cswz];
                }
            }
            #pragma unroll
            for (int m = 0; m < 4; m++)
                #pragma unroll
                for (int n = 0; n < 4; n++)
                    if (n0 + wc * 64 + n * 16 < N)
                        acc[m][n] = __builtin_amdgcn_mfma_f32_16x16x32_bf16(
                            af[m], bfr[n], acc[m][n], 0, 0, 0);
        }
        __syncthreads();
    }

    #pragma unroll
    for (int m = 0; m < 4; m++) {
        #pragma unroll
        for (int n = 0; n < 4; n++) {
            int gc = n0 + wc * 64 + n * 16 + l15;
            if (gc >= N) continue;
            int gr0 = m0 + wr * 64 + m * 16 + lhi * 4;
            #pragma unroll
            for (int j = 0; j < 4; j++) {
                int gr = gr0 + j;
                if (gr < M) {
                    if constexpr (sizeof(OutT) == 2)
                        C[(size_t)gr * ldc + gc] = (OutT)f2bf(acc[m][n][j]);
                    else
                        C[(size_t)gr * ldc + gc] = (OutT)acc[m][n][j];
                }
            }
        }
    }
}

// ---------------- big GCN: pull-gather (bf16 xw) + fused bias/relu -----------
__global__ __launch_bounds__(256) void gather_big(const int* __restrict__ esrc,
                                                  const float* __restrict__ ecoef,
                                                  const int* __restrict__ offs,
                                                  const int* __restrict__ cnt,
                                                  const ushort* __restrict__ xwb,
                                                  const float* __restrict__ dinv,
                                                  const float* __restrict__ b1,
                                                  float* __restrict__ x) {
    int wave = threadIdx.x >> 6, lane = threadIdx.x & 63;
    int dst = blockIdx.x * 4 + wave;
    if (dst >= N_NODES) return;
    int start = offs[dst], deg = cnt[dst];
    float acc[8] = {};
    for (int j = 0; j < deg; j++) {
        int src = esrc[start + j];
        float c = ecoef[start + j];
        const uint* rp = (const uint*)(xwb + (size_t)src * EMB);
        #pragma unroll
        for (int q = 0; q < 4; q++) {
            int k = lane + q * 64;           // uint index, 2 bf16 each
            if (k < EMB / 2) {
                uint u = rp[k];
                acc[2 * q]     += __uint_as_float(u << 16) * c;
                acc[2 * q + 1] += __uint_as_float(u & 0xffff0000u) * c;
            }
        }
    }
    float d2 = dinv[dst] * dinv[dst];
    const uint* sp = (const uint*)(xwb + (size_t)dst * EMB);
    float* xo = x + (size_t)dst * EMB;
    #pragma unroll
    for (int q = 0; q < 4; q++) {
        int k = lane + q * 64;
        if (k < EMB / 2) {
            uint u = sp[k];
            float s0 = acc[2 * q]     + __uint_as_float(u << 16) * d2 + b1[2 * k];
            float s1 = acc[2 * q + 1] + __uint_as_float(u & 0xffff0000u) * d2 + b1[2 * k + 1];
            *(float2*)&xo[2 * k] = make_float2(fmaxf(s0, 0.f), fmaxf(s1, 0.f));
        }
    }
}

// ---------------- row replace in temp -----------------------------------------
__global__ void set_rows(const float* __restrict__ x1s, const int* __restrict__ idxbuf,
                         float* __restrict__ temp) {
    int j = blockIdx.x, t = threadIdx.x;
    int r = idxbuf[j];
    for (int k = t; k < FEAT; k += 256)
        temp[(size_t)r * FEAT + k] = x1s[(size_t)(KTOP + j) * FEAT + k];
}

// ---------------- ConvE-ish scoring ------------------------------------------
__global__ void score_kernel(const float* __restrict__ ent, const float* __restrict__ rel,
                             const int* __restrict__ r_idx, const int* __restrict__ e1_idx,
                             const int* __restrict__ e2_idx, const float* __restrict__ conv_w,
                             const float* __restrict__ conv_b, const float* __restrict__ fc_w,
                             const float* __restrict__ fc_b, float* __restrict__ out) {
    __shared__ float cw[24];
    __shared__ float cb[8];
    int t = threadIdx.x;
    if (t < 24) cw[t] = conv_w[t];
    if (t < 8)  cb[t] = conv_b[t];
    __syncthreads();
    int wave = t >> 6, lane = t & 63;
    int b = blockIdx.x * 4 + wave;
    if (b >= BATCH) return;
    const float* r  = rel + (size_t)r_idx[b] * EMB;
    const float* e1 = ent + (size_t)e1_idx[b] * EMB;
    const float* e2 = ent + (size_t)e2_idx[b] * EMB;
    float partial = 0.f;
    for (int p = lane; p < EMB; p += 64) {
        float c0 = r[p], c1 = e1[p], c2 = e2[p];
        for (int g = 0; g < 4; g++) {
            float h0 = c0 * cw[(2 * g) * 3 + 0] + c1 * cw[(2 * g) * 3 + 1] + c2 * cw[(2 * g) * 3 + 2] + cb[2 * g];
            float h1 = c0 * cw[(2 * g + 1) * 3 + 0] + c1 * cw[(2 * g + 1) * 3 + 1] + c2 * cw[(2 * g + 1) * 3 + 2] + cb[2 * g + 1];
            partial += fmaxf(h0, h1) * fc_w[g * EMB + p];
        }
    }
    for (int off = 32; off > 0; off >>= 1) partial += __shfl_down(partial, off, 64);
    if (lane == 0) out[b] = partial + fc_b[0];
}

extern "C" void kernel_launch(void* const* d_in, const int* in_sizes, int n_in,
                              void* d_out, int out_size, void* d_ws, size_t ws_size,
                              hipStream_t stream) {
    const float* num_feature = (const float*)d_in[0];
    const float* anchor      = (const float*)d_in[1];
    const float* Wp          = (const float*)d_in[2];
    const float* bp          = (const float*)d_in[3];
    const float* Wa          = (const float*)d_in[4];
    const float* ba          = (const float*)d_in[5];
    const float* W1          = (const float*)d_in[6];
    const float* b1          = (const float*)d_in[7];
    const float* ent_emb     = (const float*)d_in[8];
    const float* rel_emb     = (const float*)d_in[9];
    const float* conv_w      = (const float*)d_in[10];
    const float* conv_b      = (const float*)d_in[11];
    const float* fc_w        = (const float*)d_in[12];
    const float* fc_b        = (const float*)d_in[13];
    const int*   edge_index  = (const int*)d_in[14];
    const int*   ra_edge     = (const int*)d_in[15];
    const int*   r_idx       = (const int*)d_in[16];
    const int*   e1_idx      = (const int*)d_in[17];
    const int*   e2_idx      = (const int*)d_in[18];

    float* out_score = (float*)d_out;                       // 4096
    float* out_x     = out_score + BATCH;                   // 50500*400
    float* out_temp  = out_x + (size_t)N_NODES * EMB;       // 50500*1000 floats

    // ---- all scratch in d_ws (~152 MB of ~1.13 GB) ----
    float* ws_f    = (float*)d_ws;
    float* logits  = ws_f;                         // 512
    int*   idxbuf  = (int*)(ws_f + 512);           // 64
    float* probsel = ws_f + 576;                   // 64
    float* dinv_s  = ws_f + 640;                   // 128
    float* raw     = ws_f + 768;                   // 100,000 (small gemm out)
    float* x1s     = ws_f + 100768;                // 100,000
    float* dinv    = ws_f + 200768;                // 50,500
    ushort* rabf   = (ushort*)(ws_f + 251268);     // 128*KP ushorts  (65,536 f)
    ushort* Btbf   = (ushort*)(ws_f + 316804);     // NP*KP ushorts   (262,144 f)
    ushort* Watbf  = (ushort*)(ws_f + 578948);     // KP*KP ushorts   (524,288 f)
    int*   cnt      = (int*)(ws_f + 1103236);      // 50,500
    int*   cursor   = cnt + N_NODES;               // 50,500
    int*   offs     = cursor + N_NODES;            // 50,500
    int*   partials = offs + N_NODES;              // 256
    int*   esrc     = partials + 256;              // 400,000
    float* ecoef    = (float*)(esrc + N_EDGES);    // 400,000
    ushort* Abf     = (ushort*)(ecoef + N_EDGES);  // MP*KP ushorts (25,886,720 f)
    ushort* xwb     = Abf + (size_t)MP * KP;       // N_NODES*EMB ushorts
    // end ≈ 38.0M floats = 152 MB

    hipMemsetAsync(x1s, 0, 100000 * sizeof(float), stream);
    hipMemsetAsync(cnt, 0, 2 * N_NODES * sizeof(int), stream);   // cnt + cursor

    // ---- fused temp-copy + A bf16 convert (single pass over num_feature) ----
    copy_convert<<<4096, 256, 0, stream>>>(num_feature, out_temp, Abf);

    // ---- small GCN pipeline (gemm via MFMA) ----
    logits_kernel<<<RELM1, 256, 0, stream>>>(num_feature, Wp, bp, logits);
    topk_kernel<<<1, 512, 0, stream>>>(logits, idxbuf, probsel);
    build_rabf<<<128, 256, 0, stream>>>(anchor, num_feature, idxbuf, probsel, rabf);
    transpose_bf16<<<dim3(16, 16), 256, 0, stream>>>(Wa, FEAT, FEAT, Watbf);
    gemm_mfma<float><<<dim3(1, 8), 256, 0, stream>>>(rabf, Watbf, raw, 2 * KTOP, FEAT, FEAT);
    small_deg_dinv<<<1, 256, 0, stream>>>(ra_edge, dinv_s);
    scatter_small<<<500, 256, 0, stream>>>(ra_edge, raw, dinv_s, x1s);
    finalize_small<<<2 * KTOP, 256, 0, stream>>>(raw, dinv_s, ba, x1s);

    // ---- big graph CSR build ----
    hist_kernel<<<(N_EDGES + 255) / 256, 256, 0, stream>>>(edge_index, cnt);
    scan_blocks<<<NB_SCAN, 256, 0, stream>>>(cnt, offs, partials, dinv);
    scan_carry<<<1, 256, 0, stream>>>(partials);
    scan_add<<<NB_SCAN, 256, 0, stream>>>(offs, partials);
    fill_csr<<<(N_EDGES + 255) / 256, 256, 0, stream>>>(edge_index, offs, cursor, dinv,
                                                        esrc, ecoef);

    // ---- big GEMM (bf16 MFMA, bf16 A staged, bf16 out) ----
    transpose_bf16<<<dim3(16, 8), 256, 0, stream>>>(W1, FEAT, EMB, Btbf);
    gemm_mfma<ushort><<<dim3(MP / 128, NP / 128), 256, 0, stream>>>(Abf, Btbf, xwb,
                                                                    N_NODES, EMB, EMB);

    // ---- aggregation (pull) with fused bias+relu ----
    gather_big<<<(N_NODES + 3) / 4, 256, 0, stream>>>(esrc, ecoef, offs, cnt, xwb, dinv,
                                                      b1, out_x);

    // ---- temp row replacement (after copy_convert + finalize_small) ----
    set_rows<<<KTOP, 256, 0, stream>>>(x1s, idxbuf, out_temp);

    // ---- scoring ----
    score_kernel<<<BATCH / 4, 256, 0, stream>>>(ent_emb, rel_emb, r_idx, e1_idx, e2_idx,
                                                conv_w, conv_b, fc_w, fc_b, out_score);
}

// Round 8
// 459.627 us; speedup vs baseline: 1.4860x; 1.0672x over previous
//
#include <hip/hip_runtime.h>
#include <hip/hip_bf16.h>

#define NUM_ENT   50000
#define NUM_RELC  500
#define KTOP      50
#define EMB       400
#define FEAT      1000
#define N_NODES   50500
#define N_EDGES   400000
#define BATCH     4096
#define RELM1     499     // NUM_REL - 1

// padded GEMM dims
#define KP   1024         // FEAT padded to mult of 64
#define MP   50560        // N_NODES padded to 395*128
#define NP   512          // EMB padded to mult of 128

#define NB_SCAN ((N_NODES + 255) / 256)   // 198
#define NB_HIST ((N_EDGES + 255) / 256)   // 1563

typedef __attribute__((ext_vector_type(8))) short short8;
typedef __attribute__((ext_vector_type(4))) float f32x4;

__device__ __forceinline__ ushort f2bf(float x) {
    __hip_bfloat16 h = __float2bfloat16(x);
    return *reinterpret_cast<ushort*>(&h);
}
__device__ __forceinline__ float bflo(uint u) { return __uint_as_float(u << 16); }
__device__ __forceinline__ float bfhi(uint u) { return __uint_as_float(u & 0xffff0000u); }

// ---------------- fused: temp = num_feature (f32) AND Abf = bf16(nf) padded --
__global__ void copy_convert(const float* __restrict__ nf, float* __restrict__ temp,
                             ushort* __restrict__ Abf) {
    size_t idx = (size_t)blockIdx.x * 256 + threadIdx.x;
    size_t stride = (size_t)gridDim.x * 256;
    size_t total = (size_t)MP * KP / 8;     // 8 elems per chunk
    for (; idx < total; idx += stride) {
        int row = (int)(idx >> 7);          // KP/8 = 128 chunks per row
        int kb  = (int)(idx & 127);
        if (row < N_NODES && kb < 125) {    // 125*8 = 1000 = FEAT
            size_t off = (size_t)row * FEAT + kb * 8;
            float4 a = *(const float4*)&nf[off];
            float4 b = *(const float4*)&nf[off + 4];
            *(float4*)&temp[off]     = a;
            *(float4*)&temp[off + 4] = b;
            ushort v[8];
            v[0] = f2bf(a.x); v[1] = f2bf(a.y); v[2] = f2bf(a.z); v[3] = f2bf(a.w);
            v[4] = f2bf(b.x); v[5] = f2bf(b.y); v[6] = f2bf(b.z); v[7] = f2bf(b.w);
            *(uint4*)&Abf[idx * 8] = *(uint4*)v;
        } else {
            uint4 z = {0u, 0u, 0u, 0u};
            *(uint4*)&Abf[idx * 8] = z;
        }
    }
}

// ---------------- fused prologue: logits | transpose Wa | transpose W1 | hist
//                  | small-graph degree+dinv  (independent work, one dispatch)
#define PB_LOG   RELM1                      // 499 logits blocks
#define PB_TWA   (PB_LOG + 256)             // 16x16 tiles of Wa
#define PB_TW1   (PB_TWA + 128)             // 16x8 tiles of W1
#define PB_HIST  (PB_TW1 + NB_HIST)
#define PB_TOTAL (PB_HIST + 1)
__global__ void prep_kernel(const float* __restrict__ nf, const float* __restrict__ Wp,
                            const float* __restrict__ bp, float* __restrict__ logits,
                            const float* __restrict__ Wa, ushort* __restrict__ Watbf,
                            const float* __restrict__ W1, ushort* __restrict__ Btbf,
                            const int* __restrict__ edge_index, int* __restrict__ cnt,
                            const int* __restrict__ ra_edge, float* __restrict__ dinv_s) {
    __shared__ float tile[64][65];
    int b = blockIdx.x, t = threadIdx.x;
    if (b < PB_LOG) {
        // ---- logits row b ----
        float* red = &tile[0][0];
        float s = 0.f;
        for (int k = t; k < FEAT; k += 256) s += nf[(size_t)b * FEAT + k] * Wp[k];
        red[t] = s; __syncthreads();
        for (int st = 128; st > 0; st >>= 1) { if (t < st) red[t] += red[t + st]; __syncthreads(); }
        if (t == 0) logits[b] = red[0] + bp[0];
    } else if (b < PB_TW1) {
        // ---- transpose-convert Wa (16x16 tiles) or W1 (16x8 tiles) ----
        const float* src; ushort* dst; int K, N, bb;
        if (b < PB_TWA) { bb = b - PB_LOG; src = Wa; dst = Watbf; K = FEAT; N = FEAT; }
        else            { bb = b - PB_TWA; src = W1; dst = Btbf;  K = FEAT; N = EMB;  }
        int k0 = (bb & 15) * 64, n0 = (bb >> 4) * 64;
        int tx = t & 63, ty = t >> 6;
        for (int i = ty; i < 64; i += 4) {
            int k = k0 + i, n = n0 + tx;
            tile[i][tx] = (k < K && n < N) ? src[(size_t)k * N + n] : 0.f;
        }
        __syncthreads();
        for (int i = ty; i < 64; i += 4) {
            int n = n0 + i, k = k0 + tx;
            dst[(size_t)n * KP + k] = f2bf(tile[tx][i]);
        }
    } else if (b < PB_HIST) {
        // ---- big-graph dst histogram ----
        int e = (b - PB_TW1) * 256 + t;
        if (e < N_EDGES) atomicAdd(&cnt[edge_index[N_EDGES + e]], 1);
    } else {
        // ---- small-graph degree + dinv ----
        int* c = (int*)&tile[0][0];
        if (t < 128) c[t] = 0;
        __syncthreads();
        for (int e = t; e < 2000; e += 256) atomicAdd(&c[ra_edge[2000 + e]], 1);
        __syncthreads();
        if (t < 2 * KTOP) dinv_s[t] = rsqrtf((float)c[t] + 1.0f);
    }
}

// ---------------- softmax over 499 + top-50 (sorted ascending) ---------------
__global__ void topk_kernel(const float* __restrict__ logits, int* __restrict__ idxbuf,
                            float* __restrict__ probsel) {
    __shared__ float l[RELM1];
    __shared__ float p[RELM1];
    __shared__ int   flag[RELM1];
    __shared__ float red[512];
    int t = threadIdx.x;  // 512 threads
    float v = (t < RELM1) ? logits[t] : -1e30f;
    if (t < RELM1) l[t] = v;
    red[t] = v; __syncthreads();
    for (int s = 256; s > 0; s >>= 1) { if (t < s) red[t] = fmaxf(red[t], red[t + s]); __syncthreads(); }
    float m = red[0]; __syncthreads();
    float e = (t < RELM1) ? expf(v - m) : 0.f;
    red[t] = e; __syncthreads();
    for (int s = 256; s > 0; s >>= 1) { if (t < s) red[t] += red[t + s]; __syncthreads(); }
    float denom = red[0];
    if (t < RELM1) p[t] = e / denom;
    __syncthreads();
    if (t < RELM1) {
        float lv = l[t]; int cnt = 0;
        for (int j = 0; j < RELM1; j++) {
            float lj = l[j];
            cnt += (lj > lv) || (lj == lv && j < t);
        }
        flag[t] = (cnt < KTOP);
    }
    __syncthreads();
    if (t == 0) {
        int n = 0;
        for (int i = 0; i < RELM1; i++)
            if (flag[i]) { idxbuf[n] = i; probsel[n] = p[i]; n++; }
    }
}

// ---------------- rabf[128][KP] = bf16(concat(anchor, nf[idx]*prob)) ---------
__global__ void build_rabf(const float* __restrict__ anchor, const float* __restrict__ nf,
                           const int* __restrict__ idxbuf, const float* __restrict__ probsel,
                           ushort* __restrict__ rabf) {
    int r = blockIdx.x, t = threadIdx.x;    // 128 blocks x 256
    const float* src = nullptr; float scale = 1.f;
    if (r < KTOP) {
        src = anchor + (size_t)r * FEAT;
    } else if (r < 2 * KTOP) {
        int j = r - KTOP;
        src = nf + (size_t)idxbuf[j] * FEAT;
        scale = probsel[j];
    }
    for (int k = t; k < KP; k += 256) {
        float v = (src != nullptr && k < FEAT) ? src[k] * scale : 0.f;
        rabf[(size_t)r * KP + k] = f2bf(v);
    }
}

// ---------------- small GCN scatter + finalize -------------------------------
__global__ void scatter_small(const int* __restrict__ ei, const float* __restrict__ raw,
                              const float* __restrict__ dinv_s, float* __restrict__ acc) {
    int wave = threadIdx.x >> 6, lane = threadIdx.x & 63;
    int e = blockIdx.x * 4 + wave;
    if (e >= 2000) return;
    int src = ei[e], dst = ei[2000 + e];
    float c = dinv_s[src] * dinv_s[dst];
    const float* rs = raw + (size_t)src * FEAT;
    float* ad = acc + (size_t)dst * FEAT;
    for (int k = lane; k < FEAT; k += 64) atomicAdd(&ad[k], rs[k] * c);
}
__global__ void finalize_small(const float* __restrict__ raw, const float* __restrict__ dinv_s,
                               const float* __restrict__ ba, float* __restrict__ x1s) {
    int r = blockIdx.x, t = threadIdx.x;
    float d2 = dinv_s[r] * dinv_s[r];
    for (int k = t; k < FEAT; k += 256) {
        float v = x1s[r * FEAT + k] + raw[r * FEAT + k] * d2 + ba[k];
        x1s[r * FEAT + k] = fmaxf(v, 0.f);
    }
}

// ---------------- big graph: CSR build ---------------------------------------
__global__ void scan_blocks(const int* __restrict__ cnt, int* __restrict__ offs,
                            int* __restrict__ partials, float* __restrict__ dinv) {
    __shared__ int s[256];
    int b = blockIdx.x, t = threadIdx.x;
    int i = b * 256 + t;
    int v = (i < N_NODES) ? cnt[i] : 0;
    if (i < N_NODES) dinv[i] = rsqrtf((float)v + 1.0f);   // fused dinv
    s[t] = v; __syncthreads();
    for (int off = 1; off < 256; off <<= 1) {
        int add = (t >= off) ? s[t - off] : 0;
        __syncthreads();
        s[t] += add;
        __syncthreads();
    }
    if (i < N_NODES) offs[i] = s[t] - v;   // exclusive scan within block
    if (t == 255) partials[b] = s[t];
}
__global__ void scan_carry(int* __restrict__ partials) {
    __shared__ int s[256];
    int t = threadIdx.x;
    int v = (t < NB_SCAN) ? partials[t] : 0;
    s[t] = v; __syncthreads();
    for (int off = 1; off < 256; off <<= 1) {
        int add = (t >= off) ? s[t - off] : 0;
        __syncthreads();
        s[t] += add;
        __syncthreads();
    }
    if (t < NB_SCAN) partials[t] = s[t] - v;   // exclusive
}
__global__ void scan_add(int* __restrict__ offs, const int* __restrict__ partials) {
    int b = blockIdx.x; int i = b * 256 + threadIdx.x;
    if (i < N_NODES) offs[i] += partials[b];
}
__global__ void fill_csr(const int* __restrict__ ei, const int* __restrict__ offs,
                         int* __restrict__ cursor, const float* __restrict__ dinv,
                         int* __restrict__ esrc, float* __restrict__ ecoef) {
    int e = blockIdx.x * 256 + threadIdx.x;
    if (e >= N_EDGES) return;
    int src = ei[e], dst = ei[N_EDGES + e];
    int pos = offs[dst] + atomicAdd(&cursor[dst], 1);
    esrc[pos] = src;
    ecoef[pos] = dinv[src] * dinv[dst];
}

// ---------------- MFMA GEMM: C[M][ldc] = A(bf16,[*][KP]) @ Bt(bf16,[*][KP])^T
// 128x128 tile, BK=64, 4 waves (2x2), global_load_lds + XOR-swizzled LDS.
// 1D grid, n-inner decomposition + bijective XCD swizzle (m204): the n-tiles
// sharing one A m-panel land consecutively on the same XCD's L2.
template <typename OutT>
__global__ __launch_bounds__(256) void gemm_mfma(const ushort* __restrict__ A,
                                                 const ushort* __restrict__ Bt,
                                                 OutT* __restrict__ C,
                                                 int M, int N, int ldc) {
    __shared__ ushort As[128 * 64];   // 16 KB, swizzled rows of 64 ushorts (128B)
    __shared__ ushort Bs[128 * 64];   // 16 KB
    int t = threadIdx.x;

    int nwg = gridDim.x;
    int orig = blockIdx.x;
    int q = nwg >> 3, r8 = nwg & 7;
    int xcd = orig & 7;
    int wgid = (xcd < r8 ? xcd * (q + 1) : r8 * (q + 1) + (xcd - r8) * q) + (orig >> 3);
    int ntiles = (N + 127) >> 7;
    int n0 = (wgid % ntiles) * 128;
    int m0 = (wgid / ntiles) * 128;

    int srow = t >> 3;                     // 0..31
    int kbx  = (t & 7) ^ (srow & 7);       // involution within 8-row stripe

    int lane = t & 63;
    int wv   = t >> 6;
    int wr   = wv >> 1, wc = wv & 1;       // wave -> 64x64 quadrant
    int l15  = lane & 15, lhi = lane >> 4;

    f32x4 acc[4][4];
    #pragma unroll
    for (int m = 0; m < 4; m++)
        #pragma unroll
        for (int n = 0; n < 4; n++) acc[m][n] = (f32x4){0.f, 0.f, 0.f, 0.f};

    for (int kt = 0; kt < KP / 64; kt++) {
        int k0 = kt * 64;
        #pragma unroll
        for (int r = 0; r < 4; r++) {
            int row = r * 32 + srow;
            const ushort* ga = A  + (size_t)(m0 + row) * KP + k0 + kbx * 8;
            const ushort* gb = Bt + (size_t)(n0 + row) * KP + k0 + kbx * 8;
            ushort* la = &As[(size_t)row * 64 + (t & 7) * 8];
            ushort* lb = &Bs[(size_t)row * 64 + (t & 7) * 8];
            __builtin_amdgcn_global_load_lds(
                (const __attribute__((address_space(1))) unsigned int*)ga,
                (__attribute__((address_space(3))) unsigned int*)la, 16, 0, 0);
            __builtin_amdgcn_global_load_lds(
                (const __attribute__((address_space(1))) unsigned int*)gb,
                (__attribute__((address_space(3))) unsigned int*)lb, 16, 0, 0);
        }
        __syncthreads();

        #pragma unroll
        for (int ks = 0; ks < 2; ks++) {
            int cswz = ((ks * 64 + lhi * 16) ^ ((lane & 7) << 4)) >> 1;
            short8 af[4], bfr[4];
            #pragma unroll
            for (int m = 0; m < 4; m++) {
                int rowl = wr * 64 + m * 16 + l15;
                af[m] = *(const short8*)&As[rowl * 64 + cswz];
            }
            #pragma unroll
            for (int n = 0; n < 4; n++) {
                if (n0 + wc * 64 + n * 16 < N) {          // prune padded n-frags
                    int rowl = wc * 64 + n * 16 + l15;
                    bfr[n] = *(const short8*)&Bs[rowl * 64 + cswz];
                }
            }
            #pragma unroll
            for (int m = 0; m < 4; m++)
                #pragma unroll
                for (int n = 0; n < 4; n++)
                    if (n0 + wc * 64 + n * 16 < N)
                        acc[m][n] = __builtin_amdgcn_mfma_f32_16x16x32_bf16(
                            af[m], bfr[n], acc[m][n], 0, 0, 0);
        }
        __syncthreads();
    }

    #pragma unroll
    for (int m = 0; m < 4; m++) {
        #pragma unroll
        for (int n = 0; n < 4; n++) {
            int gc = n0 + wc * 64 + n * 16 + l15;
            if (gc >= N) continue;
            int gr0 = m0 + wr * 64 + m * 16 + lhi * 4;
            #pragma unroll
            for (int j = 0; j < 4; j++) {
                int gr = gr0 + j;
                if (gr < M) {
                    if constexpr (sizeof(OutT) == 2)
                        C[(size_t)gr * ldc + gc] = (OutT)f2bf(acc[m][n][j]);
                    else
                        C[(size_t)gr * ldc + gc] = (OutT)acc[m][n][j];
                }
            }
        }
    }
}

// ---------------- big GCN: pull-gather (bf16 xw, dwordx4) + bias/relu --------
__global__ __launch_bounds__(256) void gather_big(const int* __restrict__ esrc,
                                                  const float* __restrict__ ecoef,
                                                  const int* __restrict__ offs,
                                                  const int* __restrict__ cnt,
                                                  const ushort* __restrict__ xwb,
                                                  const float* __restrict__ dinv,
                                                  const float* __restrict__ b1,
                                                  float* __restrict__ x) {
    int wave = threadIdx.x >> 6, lane = threadIdx.x & 63;
    int dst = blockIdx.x * 4 + wave;
    if (dst >= N_NODES) return;
    int start = offs[dst], deg = cnt[dst];
    bool act = lane < EMB / 8;               // 50 lanes x 8 bf16 = 400
    float acc[8] = {};
    for (int j = 0; j < deg; j++) {
        int src = esrc[start + j];
        float c = ecoef[start + j];
        if (act) {
            uint4 u = *(const uint4*)(xwb + (size_t)src * EMB + lane * 8);
            acc[0] += bflo(u.x) * c; acc[1] += bfhi(u.x) * c;
            acc[2] += bflo(u.y) * c; acc[3] += bfhi(u.y) * c;
            acc[4] += bflo(u.z) * c; acc[5] += bfhi(u.z) * c;
            acc[6] += bflo(u.w) * c; acc[7] += bfhi(u.w) * c;
        }
    }
    if (!act) return;
    float d2 = dinv[dst] * dinv[dst];
    uint4 u = *(const uint4*)(xwb + (size_t)dst * EMB + lane * 8);
    const float* bp = b1 + lane * 8;
    float* xo = x + (size_t)dst * EMB + lane * 8;
    float4 o0, o1;
    o0.x = fmaxf(acc[0] + bflo(u.x) * d2 + bp[0], 0.f);
    o0.y = fmaxf(acc[1] + bfhi(u.x) * d2 + bp[1], 0.f);
    o0.z = fmaxf(acc[2] + bflo(u.y) * d2 + bp[2], 0.f);
    o0.w = fmaxf(acc[3] + bfhi(u.y) * d2 + bp[3], 0.f);
    o1.x = fmaxf(acc[4] + bflo(u.z) * d2 + bp[4], 0.f);
    o1.y = fmaxf(acc[5] + bfhi(u.z) * d2 + bp[5], 0.f);
    o1.z = fmaxf(acc[6] + bflo(u.w) * d2 + bp[6], 0.f);
    o1.w = fmaxf(acc[7] + bfhi(u.w) * d2 + bp[7], 0.f);
    *(float4*)&xo[0] = o0;
    *(float4*)&xo[4] = o1;
}

// ---------------- row replace in temp -----------------------------------------
__global__ void set_rows(const float* __restrict__ x1s, const int* __restrict__ idxbuf,
                         float* __restrict__ temp) {
    int j = blockIdx.x, t = threadIdx.x;
    int r = idxbuf[j];
    for (int k = t; k < FEAT; k += 256)
        temp[(size_t)r * FEAT + k] = x1s[(size_t)(KTOP + j) * FEAT + k];
}

// ---------------- ConvE-ish scoring ------------------------------------------
__global__ void score_kernel(const float* __restrict__ ent, const float* __restrict__ rel,
                             const int* __restrict__ r_idx, const int* __restrict__ e1_idx,
                             const int* __restrict__ e2_idx, const float* __restrict__ conv_w,
                             const float* __restrict__ conv_b, const float* __restrict__ fc_w,
                             const float* __restrict__ fc_b, float* __restrict__ out) {
    __shared__ float cw[24];
    __shared__ float cb[8];
    int t = threadIdx.x;
    if (t < 24) cw[t] = conv_w[t];
    if (t < 8)  cb[t] = conv_b[t];
    __syncthreads();
    int wave = t >> 6, lane = t & 63;
    int b = blockIdx.x * 4 + wave;
    if (b >= BATCH) return;
    const float* r  = rel + (size_t)r_idx[b] * EMB;
    const float* e1 = ent + (size_t)e1_idx[b] * EMB;
    const float* e2 = ent + (size_t)e2_idx[b] * EMB;
    float partial = 0.f;
    for (int p = lane; p < EMB; p += 64) {
        float c0 = r[p], c1 = e1[p], c2 = e2[p];
        for (int g = 0; g < 4; g++) {
            float h0 = c0 * cw[(2 * g) * 3 + 0] + c1 * cw[(2 * g) * 3 + 1] + c2 * cw[(2 * g) * 3 + 2] + cb[2 * g];
            float h1 = c0 * cw[(2 * g + 1) * 3 + 0] + c1 * cw[(2 * g + 1) * 3 + 1] + c2 * cw[(2 * g + 1) * 3 + 2] + cb[2 * g + 1];
            partial += fmaxf(h0, h1) * fc_w[g * EMB + p];
        }
    }
    for (int off = 32; off > 0; off >>= 1) partial += __shfl_down(partial, off, 64);
    if (lane == 0) out[b] = partial + fc_b[0];
}

extern "C" void kernel_launch(void* const* d_in, const int* in_sizes, int n_in,
                              void* d_out, int out_size, void* d_ws, size_t ws_size,
                              hipStream_t stream) {
    const float* num_feature = (const float*)d_in[0];
    const float* anchor      = (const float*)d_in[1];
    const float* Wp          = (const float*)d_in[2];
    const float* bp          = (const float*)d_in[3];
    const float* Wa          = (const float*)d_in[4];
    const float* ba          = (const float*)d_in[5];
    const float* W1          = (const float*)d_in[6];
    const float* b1          = (const float*)d_in[7];
    const float* ent_emb     = (const float*)d_in[8];
    const float* rel_emb     = (const float*)d_in[9];
    const float* conv_w      = (const float*)d_in[10];
    const float* conv_b      = (const float*)d_in[11];
    const float* fc_w        = (const float*)d_in[12];
    const float* fc_b        = (const float*)d_in[13];
    const int*   edge_index  = (const int*)d_in[14];
    const int*   ra_edge     = (const int*)d_in[15];
    const int*   r_idx       = (const int*)d_in[16];
    const int*   e1_idx      = (const int*)d_in[17];
    const int*   e2_idx      = (const int*)d_in[18];

    float* out_score = (float*)d_out;                       // 4096
    float* out_x     = out_score + BATCH;                   // 50500*400
    float* out_temp  = out_x + (size_t)N_NODES * EMB;       // 50500*1000 floats

    // ---- all scratch in d_ws (~152 MB of ~1.13 GB) ----
    float* ws_f    = (float*)d_ws;
    float* logits  = ws_f;                         // 512
    int*   idxbuf  = (int*)(ws_f + 512);           // 64
    float* probsel = ws_f + 576;                   // 64
    float* dinv_s  = ws_f + 640;                   // 128
    float* raw     = ws_f + 768;                   // 100,000 (small gemm out)
    float* x1s     = ws_f + 100768;                // 100,000
    float* dinv    = ws_f + 200768;                // 50,500
    ushort* rabf   = (ushort*)(ws_f + 251268);     // 128*KP ushorts  (65,536 f)
    ushort* Btbf   = (ushort*)(ws_f + 316804);     // NP*KP ushorts   (262,144 f)
    ushort* Watbf  = (ushort*)(ws_f + 578948);     // KP*KP ushorts   (524,288 f)
    int*   cnt      = (int*)(ws_f + 1103236);      // 50,500
    int*   cursor   = cnt + N_NODES;               // 50,500
    int*   offs     = cursor + N_NODES;            // 50,500
    int*   partials = offs + N_NODES;              // 256
    int*   esrc     = partials + 256;              // 400,000
    float* ecoef    = (float*)(esrc + N_EDGES);    // 400,000
    ushort* Abf     = (ushort*)(ecoef + N_EDGES);  // MP*KP ushorts (25,886,720 f)
    ushort* xwb     = Abf + (size_t)MP * KP;       // N_NODES*EMB ushorts
    // end ≈ 38.0M floats = 152 MB

    hipMemsetAsync(x1s, 0, 100000 * sizeof(float), stream);
    hipMemsetAsync(cnt, 0, 2 * N_NODES * sizeof(int), stream);   // cnt + cursor

    // ---- fused temp-copy + A bf16 convert (single pass over num_feature) ----
    copy_convert<<<4096, 256, 0, stream>>>(num_feature, out_temp, Abf);

    // ---- fused prologue (logits | transposes | hist | small deg) ----
    prep_kernel<<<PB_TOTAL, 256, 0, stream>>>(num_feature, Wp, bp, logits,
                                              Wa, Watbf, W1, Btbf,
                                              edge_index, cnt, ra_edge, dinv_s);

    // ---- small GCN pipeline (gemm via MFMA) ----
    topk_kernel<<<1, 512, 0, stream>>>(logits, idxbuf, probsel);
    build_rabf<<<128, 256, 0, stream>>>(anchor, num_feature, idxbuf, probsel, rabf);
    gemm_mfma<float><<<8, 256, 0, stream>>>(rabf, Watbf, raw, 2 * KTOP, FEAT, FEAT);
    scatter_small<<<500, 256, 0, stream>>>(ra_edge, raw, dinv_s, x1s);
    finalize_small<<<2 * KTOP, 256, 0, stream>>>(raw, dinv_s, ba, x1s);

    // ---- big graph CSR build ----
    scan_blocks<<<NB_SCAN, 256, 0, stream>>>(cnt, offs, partials, dinv);
    scan_carry<<<1, 256, 0, stream>>>(partials);
    scan_add<<<NB_SCAN, 256, 0, stream>>>(offs, partials);
    fill_csr<<<NB_HIST, 256, 0, stream>>>(edge_index, offs, cursor, dinv, esrc, ecoef);

    // ---- big GEMM (bf16 MFMA, n-inner + XCD swizzle) ----
    gemm_mfma<ushort><<<(MP / 128) * (NP / 128), 256, 0, stream>>>(Abf, Btbf, xwb,
                                                                   N_NODES, EMB, EMB);

    // ---- aggregation (pull) with fused bias+relu ----
    gather_big<<<(N_NODES + 3) / 4, 256, 0, stream>>>(esrc, ecoef, offs, cnt, xwb, dinv,
                                                      b1, out_x);

    // ---- temp row replacement (after copy_convert + finalize_small) ----
    set_rows<<<KTOP, 256, 0, stream>>>(x1s, idxbuf, out_temp);

    // ---- scoring ----
    score_kernel<<<BATCH / 4, 256, 0, stream>>>(ent_emb, rel_emb, r_idx, e1_idx, e2_idx,
                                                conv_w, conv_b, fc_w, fc_b, out_score);
}